// Round 3
// baseline (453.596 us; speedup 1.0000x reference)
//
#include <hip/hip_runtime.h>

// MultiHeadSelfAttention: BS=4, S=2048, DIM=768, H=12, DH=64
// R3: barrier-free flash attention (per-wave query ownership, intra-wave P transpose
//     through private LDS, no-max softmax), XCD-swizzled attn grid, merged QKV GEMM
//     with fused fp32->bf16 A-staging, 128x64 tiles everywhere.
// MFMA layouts (learn_hip m89/m91): A/B-frag: [m|n = lane&15][k = quad*8+j]
//                                   C/D: col = lane&15, row = quad*4 + reg

#define BSZ 4
#define SEQ 2048
#define DIMD 768
#define NHD 12
#define MTOT (BSZ*SEQ)      // 8192
#define WELEM (DIMD*DIMD)   // 589824

typedef __bf16 bf16;
typedef __attribute__((ext_vector_type(8))) __bf16 bf16x8;
typedef __attribute__((ext_vector_type(4))) __bf16 bf16x4;
typedef __attribute__((ext_vector_type(4))) float f32x4;

__device__ __forceinline__ f32x4 mfma_bf16(bf16x8 a, bf16x8 b, f32x4 c) {
    return __builtin_amdgcn_mfma_f32_16x16x32_bf16(a, b, c, 0, 0, 0);
}

__device__ __forceinline__ void async16(const bf16* g, bf16* l) {
    __builtin_amdgcn_global_load_lds(
        (const __attribute__((address_space(1))) unsigned int*)g,
        (__attribute__((address_space(3))) unsigned int*)l, 16, 0, 0);
}

// ---------------- weight fp32 -> bf16 ----------------
__global__ __launch_bounds__(256) void convert_w_kernel(
    const float* __restrict__ w0, const float* __restrict__ w1,
    const float* __restrict__ w2, const float* __restrict__ w3,
    bf16* __restrict__ out) {
    const int z = blockIdx.y;
    const float* src = (z == 0) ? w0 : (z == 1) ? w1 : (z == 2) ? w2 : w3;
    const int i = (blockIdx.x * 256 + threadIdx.x) * 4;
    float4 v = *(const float4*)(src + i);
    bf16x4 o;
    o[0] = (bf16)v.x; o[1] = (bf16)v.y; o[2] = (bf16)v.z; o[3] = (bf16)v.w;
    *(bf16x4*)(out + (size_t)z * WELEM + i) = o;
}

// ---------------- merged QKV projection ----------------
// grid (64, 36): z = by/12 selects {query,key_t,value} & W slice; f0 = (by%12)*64;
// m0 = bx*128 (rows of X). Tile 128(m=rows) x 64(n=feat). A staged with fused
// fp32->bf16 convert; B (weights) via global_load_lds w16. XOR-8 col-block swizzle.
// z<2: out [b][h][s][dh]; z=2: out [b][h][dh][s] (transposed via LDS).
__global__ __launch_bounds__(256, 4) void qkv_kernel(
    const float* __restrict__ xq, const float* __restrict__ xk, const float* __restrict__ xv,
    const bf16* __restrict__ W,
    const float* __restrict__ bq, const float* __restrict__ bk, const float* __restrict__ bv,
    bf16* __restrict__ Qb, bf16* __restrict__ Kb, bf16* __restrict__ Vb) {
    __shared__ __align__(16) bf16 smem[128 * 64 + 64 * 64];   // 24.5 KB
    bf16* As = smem;
    bf16* Bs = smem + 128 * 64;
    const int tid = threadIdx.x;
    const int lane = tid & 63, wv = tid >> 6;
    const int quad = lane >> 4, l16 = lane & 15;
    const int wr = wv >> 1, wc = wv & 1;
    const int rr = lane >> 3, cbl = lane & 7;
    const int arow = tid >> 1, acb = (tid & 1) * 4;
    const int z = blockIdx.y / 12;
    const int f0 = (blockIdx.y % 12) * 64;
    const int m0 = blockIdx.x * 128;
    const float* X    = (z == 0) ? xq : (z == 1) ? xk : xv;
    const float* bias = (z == 0) ? bq : (z == 1) ? bk : bv;
    const bf16*  Wz   = W + (size_t)z * WELEM;
    const float scale = (z == 0) ? 0.125f : 1.0f;

    f32x4 acc[4][2] = {};
    for (int kt = 0; kt < 12; ++kt) {
        if (kt) __syncthreads();
        // A: fp32 load + convert + swizzled LDS write (128 rows x 64 cols)
        {
            const float* ap = X + (size_t)(m0 + arow) * DIMD + kt * 64 + acb * 8;
            for (int i = 0; i < 4; ++i) {
                float4 u = *(const float4*)(ap + i * 8);
                float4 w = *(const float4*)(ap + i * 8 + 4);
                bf16x8 p;
                p[0] = (bf16)u.x; p[1] = (bf16)u.y; p[2] = (bf16)u.z; p[3] = (bf16)u.w;
                p[4] = (bf16)w.x; p[5] = (bf16)w.y; p[6] = (bf16)w.z; p[7] = (bf16)w.w;
                *(bf16x8*)(As + arow * 64 + ((acb + i) ^ (arow & 7)) * 8) = p;
            }
        }
        // B: weights async (64 rows x 64 cols)
        for (int c = 0; c < 2; ++c) {
            const int row = c * 32 + wv * 8 + rr;
            const int cb = cbl ^ (row & 7);
            async16(Wz + (size_t)(f0 + row) * DIMD + kt * 64 + cb * 8,
                    Bs + row * 64 + cbl * 8);
        }
        __syncthreads();
        for (int ks = 0; ks < 2; ++ks) {
            const int kc = ((ks * 4 + quad) ^ (l16 & 7)) * 8;
            bf16x8 af[4], bfr[2];
            for (int t = 0; t < 4; ++t)
                af[t] = *(const bf16x8*)(As + (wr * 64 + t * 16 + l16) * 64 + kc);
            for (int t = 0; t < 2; ++t)
                bfr[t] = *(const bf16x8*)(Bs + (wc * 32 + t * 16 + l16) * 64 + kc);
            for (int ti = 0; ti < 4; ++ti)
                for (int tj = 0; tj < 2; ++tj)
                    acc[ti][tj] = mfma_bf16(af[ti], bfr[tj], acc[ti][tj]);
        }
    }
    __syncthreads();
    const int h = f0 >> 6;          // f0 is 64-aligned: one head per block
    const int bb = m0 >> 11, sbase = m0 & 2047;
    if (z < 2) {
        bf16* Ot = smem;            // [128 s][72] (stride 72, 16B-aligned rows)
        for (int ti = 0; ti < 4; ++ti)
            for (int tj = 0; tj < 2; ++tj) {
                const int fl = wc * 32 + tj * 16 + l16;
                const float bvl = bias[f0 + fl];
                const int sl = wr * 64 + ti * 16 + quad * 4;
                for (int r = 0; r < 4; ++r)
                    Ot[(sl + r) * 72 + fl] = (bf16)((acc[ti][tj][r] + bvl) * scale);
            }
        __syncthreads();
        bf16* Out = (z == 0) ? Qb : Kb;
        for (int it = 0; it < 4; ++it) {
            const int u = it * 256 + tid;       // 1024 16B-units
            const int s = u >> 3, c8 = u & 7;
            *(bf16x8*)&Out[((size_t)(bb * NHD + h) * SEQ + sbase + s) * 64 + c8 * 8] =
                *(const bf16x8*)&Ot[s * 72 + c8 * 8];
        }
    } else {
        bf16* Ot = smem;            // [64 f][136] transposed (stride 136, 16B-aligned)
        for (int ti = 0; ti < 4; ++ti)
            for (int tj = 0; tj < 2; ++tj) {
                const int fl = wc * 32 + tj * 16 + l16;
                const float bvl = bias[f0 + fl];
                const int sl = wr * 64 + ti * 16 + quad * 4;
                bf16x4 pk;
                for (int r = 0; r < 4; ++r) pk[r] = (bf16)(acc[ti][tj][r] + bvl);
                *(bf16x4*)&Ot[fl * 136 + sl] = pk;
            }
        __syncthreads();
        for (int it = 0; it < 4; ++it) {
            const int u = it * 256 + tid;       // 64 rows x 16 units
            const int f = u >> 4, c8 = u & 15;
            *(bf16x8*)&Vb[((size_t)(bb * NHD + h) * 64 + f) * SEQ + sbase + c8 * 8] =
                *(const bf16x8*)&Ot[f * 136 + c8 * 8];
        }
    }
}

// ---------------- barrier-free flash attention ----------------
// grid (768) linear, XCD-swizzled: 16 q-tiles of one (b,h) stay on one XCD.
// block 256 = 4 waves; each wave owns 32 queries (2 strips of 16) end-to-end.
// Phase 1: S^T = K.Q^T (K frags direct global). No-max softmax: p = exp(s + maskadd).
// P transpose via per-wave private LDS (XOR-swizzled 16B units) — intra-wave only.
// Phase 2: O^T = V^T.P^T (V^T frags direct global), all 64 dh per wave.
__global__ __launch_bounds__(256, 4) void attn_kernel(
    const bf16* __restrict__ Qb, const bf16* __restrict__ Kb, const bf16* __restrict__ Vb,
    const int* __restrict__ mask, bf16* __restrict__ CTX) {
    __shared__ __align__(16) bf16 Ps[4 * 32 * 72];   // per-wave [32][72]
    __shared__ float sadd[SEQ];
    __shared__ int anyz_s;
    const int tid = threadIdx.x;
    const int lane = tid & 63, wv = tid >> 6, quad = lane >> 4, l16 = lane & 15;
    const int lin = blockIdx.x;
    const int xcd = lin & 7, j = lin >> 3;
    const int qt = j & 15, pg = j >> 4;
    const int p = pg * 8 + xcd;                      // 0..47
    const int b = p / NHD, h = p % NHD;
    const int bh = b * NHD + h;
    if (tid == 0) anyz_s = 0;
    __syncthreads();
    {
        int4 m0v = *(const int4*)(mask + b * SEQ + tid * 8);
        int4 m1v = *(const int4*)(mask + b * SEQ + tid * 8 + 4);
        float4 f0, f1;
        f0.x = m0v.x ? 0.f : -1e30f; f0.y = m0v.y ? 0.f : -1e30f;
        f0.z = m0v.z ? 0.f : -1e30f; f0.w = m0v.w ? 0.f : -1e30f;
        f1.x = m1v.x ? 0.f : -1e30f; f1.y = m1v.y ? 0.f : -1e30f;
        f1.z = m1v.z ? 0.f : -1e30f; f1.w = m1v.w ? 0.f : -1e30f;
        *(float4*)&sadd[tid * 8] = f0;
        *(float4*)&sadd[tid * 8 + 4] = f1;
        if (!(m0v.x && m0v.y && m0v.z && m0v.w && m1v.x && m1v.y && m1v.z && m1v.w))
            anyz_s = 1;
    }
    // loop-invariant Q fragments (B operand), 2 strips of 16 queries
    bf16x8 qf0[2], qf1[2];
    for (int st = 0; st < 2; ++st) {
        const bf16* qp = Qb + ((size_t)bh * SEQ + qt * 128 + wv * 32 + st * 16 + l16) * 64;
        qf0[st] = *(const bf16x8*)(qp + quad * 8);
        qf1[st] = *(const bf16x8*)(qp + 32 + quad * 8);
    }
    const bf16* Kp = Kb + (size_t)bh * SEQ * 64 + (size_t)l16 * 64 + quad * 8;
    const bf16* Vp = Vb + (size_t)bh * 64 * SEQ + quad * 8;
    bf16* Pw = Ps + wv * (32 * 72);
    const int swz = l16 & 3;
    f32x4 acc[4][2] = {};                            // [dh-group][strip]
    float rs[2] = {0.f, 0.f};
    __syncthreads();
    const int az = anyz_s;
    for (int kt = 0; kt < SEQ / 64; ++kt) {
        const int k0 = kt * 64;
        // K fragments direct from global (A operand: m=key, k=dh)
        bf16x8 kf0[4], kf1[4];
        for (int jj = 0; jj < 4; ++jj) {
            const bf16* kp = Kp + (size_t)(k0 + jj * 16) * 64;
            kf0[jj] = *(const bf16x8*)kp;
            kf1[jj] = *(const bf16x8*)(kp + 32);
        }
        for (int st = 0; st < 2; ++st) {
            f32x4 sc[4];
            for (int jj = 0; jj < 4; ++jj) {
                f32x4 zf = {};
                zf = mfma_bf16(kf0[jj], qf0[st], zf);
                sc[jj] = mfma_bf16(kf1[jj], qf1[st], zf);
            }
            if (az)
                for (int jj = 0; jj < 4; ++jj) {
                    const float4 sa = *(const float4*)&sadd[k0 + jj * 16 + quad * 4];
                    sc[jj][0] += sa.x; sc[jj][1] += sa.y;
                    sc[jj][2] += sa.z; sc[jj][3] += sa.w;
                }
            float tsum = 0.f;
            for (int jj = 0; jj < 4; ++jj) {
                bf16x4 pk;
                for (int r = 0; r < 4; ++r) {
                    const float pv = __expf(sc[jj][r]);
                    tsum += pv;
                    pk[r] = (bf16)pv;
                }
                const int u = (2 * jj + (quad >> 1)) ^ swz;
                *(bf16x4*)&Pw[(st * 16 + l16) * 72 + u * 8 + (quad & 1) * 4] = pk;
            }
            rs[st] += tsum;
        }
        // V^T fragments direct from global (A operand: m=dh, k=key), all 4 dh groups
        bf16x8 vf0[4], vf1[4];
        for (int ti = 0; ti < 4; ++ti) {
            const bf16* vp = Vp + (size_t)(ti * 16 + l16) * SEQ + k0;
            vf0[ti] = *(const bf16x8*)vp;
            vf1[ti] = *(const bf16x8*)(vp + 32);
        }
        // P fragments (B operand) from own wave's scratch — same-wave, no barrier
        bf16x8 pf0[2], pf1[2];
        for (int st = 0; st < 2; ++st) {
            pf0[st] = *(const bf16x8*)&Pw[(st * 16 + l16) * 72 + (quad ^ swz) * 8];
            pf1[st] = *(const bf16x8*)&Pw[(st * 16 + l16) * 72 + (4 | (quad ^ swz)) * 8];
        }
        for (int ti = 0; ti < 4; ++ti)
            for (int st = 0; st < 2; ++st) {
                f32x4 c = acc[ti][st];
                c = mfma_bf16(vf0[ti], pf0[st], c);
                c = mfma_bf16(vf1[ti], pf1[st], c);
                acc[ti][st] = c;
            }
    }
    float inv[2];
    for (int st = 0; st < 2; ++st) {
        float s = rs[st];
        s += __shfl_xor(s, 16);
        s += __shfl_xor(s, 32);
        inv[st] = 1.0f / s;
    }
    for (int ti = 0; ti < 4; ++ti)
        for (int st = 0; st < 2; ++st) {
            bf16x4 pk;
            for (int r = 0; r < 4; ++r) pk[r] = (bf16)(acc[ti][st][r] * inv[st]);
            const int s = qt * 128 + wv * 32 + st * 16 + l16;
            *(bf16x4*)&CTX[(size_t)(b * SEQ + s) * DIMD + h * 64 + ti * 16 + quad * 4] = pk;
        }
}

// ---------------- output projection: CTX(bf16) @ Wo^T + b -> fp32 ----------------
// Tile 128x64, grid (64, 12) = 768 blocks.
__global__ __launch_bounds__(256, 4) void oproj_kernel(
    const bf16* __restrict__ ctx, const bf16* __restrict__ wo,
    const float* __restrict__ bo, float* __restrict__ out) {
    __shared__ __align__(16) bf16 smem[128 * 64 + 64 * 64];
    bf16* As = smem;
    bf16* Bs = smem + 128 * 64;
    const int tid = threadIdx.x;
    const int lane = tid & 63, wv = tid >> 6;
    const int quad = lane >> 4, l16 = lane & 15;
    const int wr = wv >> 1, wc = wv & 1;
    const int rr = lane >> 3, cbl = lane & 7;
    const int m0 = blockIdx.x * 128, f0 = blockIdx.y * 64;
    f32x4 acc[4][2] = {};
    for (int kt = 0; kt < 12; ++kt) {
        if (kt) __syncthreads();
        for (int c = 0; c < 4; ++c) {
            const int row = c * 32 + wv * 8 + rr;
            const int cb = cbl ^ (row & 7);
            async16(ctx + (size_t)(m0 + row) * DIMD + kt * 64 + cb * 8,
                    As + row * 64 + cbl * 8);
        }
        for (int c = 0; c < 2; ++c) {
            const int row = c * 32 + wv * 8 + rr;
            const int cb = cbl ^ (row & 7);
            async16(wo + (size_t)(f0 + row) * DIMD + kt * 64 + cb * 8,
                    Bs + row * 64 + cbl * 8);
        }
        __syncthreads();
        for (int ks = 0; ks < 2; ++ks) {
            const int kc = ((ks * 4 + quad) ^ (l16 & 7)) * 8;
            bf16x8 af[4], bfr[2];
            for (int t = 0; t < 4; ++t)
                af[t] = *(const bf16x8*)(As + (wr * 64 + t * 16 + l16) * 64 + kc);
            for (int t = 0; t < 2; ++t)
                bfr[t] = *(const bf16x8*)(Bs + (wc * 32 + t * 16 + l16) * 64 + kc);
            for (int ti = 0; ti < 4; ++ti)
                for (int tj = 0; tj < 2; ++tj)
                    acc[ti][tj] = mfma_bf16(af[ti], bfr[tj], acc[ti][tj]);
        }
    }
    for (int ti = 0; ti < 4; ++ti) {
        const int rowb = m0 + wr * 64 + ti * 16 + quad * 4;
        for (int tj = 0; tj < 2; ++tj) {
            const int feat = f0 + wc * 32 + tj * 16 + l16;
            const float bvl = bo[feat];
            for (int r = 0; r < 4; ++r)
                out[(size_t)(rowb + r) * DIMD + feat] = acc[ti][tj][r] + bvl;
        }
    }
}

extern "C" void kernel_launch(void* const* d_in, const int* in_sizes, int n_in,
                              void* d_out, int out_size, void* d_ws, size_t ws_size,
                              hipStream_t stream) {
    const float* query = (const float*)d_in[0];
    const float* key_t = (const float*)d_in[1];
    const float* value = (const float*)d_in[2];
    const int*   mask  = (const int*)d_in[3];
    const float* q_w = (const float*)d_in[4];
    const float* q_b = (const float*)d_in[5];
    const float* k_w = (const float*)d_in[6];
    const float* k_b = (const float*)d_in[7];
    const float* v_w = (const float*)d_in[8];
    const float* v_b = (const float*)d_in[9];
    const float* o_w = (const float*)d_in[10];
    const float* o_b = (const float*)d_in[11];
    float* out = (float*)d_out;

    bf16* ws  = (bf16*)d_ws;
    bf16* W   = ws;                                  // 4 x WELEM
    bf16* Qb  = ws + (size_t)4 * WELEM;              // [b][h][s][dh]
    bf16* Kb  = Qb + (size_t)MTOT * DIMD;            // [b][h][s][dh]
    bf16* Vb  = Kb + (size_t)MTOT * DIMD;            // [b][h][dh][s]
    bf16* CTX = Vb + (size_t)MTOT * DIMD;            // [b*s][dim]

    convert_w_kernel<<<dim3(WELEM / 1024, 4), 256, 0, stream>>>(q_w, k_w, v_w, o_w, W);
    qkv_kernel<<<dim3(64, 36), 256, 0, stream>>>(
        query, key_t, value, W, q_b, k_b, v_b, Qb, Kb, Vb);
    attn_kernel<<<768, 256, 0, stream>>>(Qb, Kb, Vb, mask, CTX);
    oproj_kernel<<<dim3(64, 12), 256, 0, stream>>>(
        CTX, W + (size_t)3 * WELEM, o_b, out);
}

// Round 6
// 341.932 us; speedup vs baseline: 1.3266x; 1.3266x over previous
//
#include <hip/hip_runtime.h>

// MultiHeadSelfAttention: BS=4, S=2048, DIM=768, H=12, DH=64
// R6 (bisect + recover): R4's merged qkv (64,18 grid, fused fp32->bf16 A-staging)
//     + R2's PROVEN attention (dbuf P, online softmax, 1 barrier/iter) with only
//     the R3-proven XCD block-decode substituted + R3-proven oproj.
// MFMA layouts (learn_hip m89/m91): A/B-frag: [m|n = lane&15][k = quad*8+j]
//                                   C/D: col = lane&15, row = quad*4 + reg

#define BSZ 4
#define SEQ 2048
#define DIMD 768
#define NHD 12
#define MTOT (BSZ*SEQ)      // 8192
#define WELEM (DIMD*DIMD)   // 589824

typedef __bf16 bf16;
typedef __attribute__((ext_vector_type(8))) __bf16 bf16x8;
typedef __attribute__((ext_vector_type(4))) __bf16 bf16x4;
typedef __attribute__((ext_vector_type(4))) float f32x4;

__device__ __forceinline__ f32x4 mfma_bf16(bf16x8 a, bf16x8 b, f32x4 c) {
    return __builtin_amdgcn_mfma_f32_16x16x32_bf16(a, b, c, 0, 0, 0);
}

__device__ __forceinline__ void async16(const bf16* g, bf16* l) {
    __builtin_amdgcn_global_load_lds(
        (const __attribute__((address_space(1))) unsigned int*)g,
        (__attribute__((address_space(3))) unsigned int*)l, 16, 0, 0);
}

// ---------------- weight fp32 -> bf16 ----------------
__global__ __launch_bounds__(256) void convert_w_kernel(
    const float* __restrict__ w0, const float* __restrict__ w1,
    const float* __restrict__ w2, const float* __restrict__ w3,
    bf16* __restrict__ out) {
    const int z = blockIdx.y;
    const float* src = (z == 0) ? w0 : (z == 1) ? w1 : (z == 2) ? w2 : w3;
    const int i = (blockIdx.x * 256 + threadIdx.x) * 4;
    float4 v = *(const float4*)(src + i);
    bf16x4 o;
    o[0] = (bf16)v.x; o[1] = (bf16)v.y; o[2] = (bf16)v.z; o[3] = (bf16)v.w;
    *(bf16x4*)(out + (size_t)z * WELEM + i) = o;
}

// ---------------- merged QKV projection, 128x128 tiles (R4 verbatim) ----------------
// grid (64, 18): m0 = bx*128 (rows of X); z = by/6; n0 = (by%6)*128 (features).
// A (X fp32) staged with fused convert; B (W bf16) via global_load_lds w16.
// z<2: out [b][h][s][dh] (Q scaled 1/8); z=2: out [b][h][dh][s].
__global__ __launch_bounds__(256, 3) void qkv_kernel(
    const float* __restrict__ xq, const float* __restrict__ xk, const float* __restrict__ xv,
    const bf16* __restrict__ W,
    const float* __restrict__ bq, const float* __restrict__ bk, const float* __restrict__ bv,
    bf16* __restrict__ Qb, bf16* __restrict__ Kb, bf16* __restrict__ Vb) {
    __shared__ __align__(16) bf16 smem[128 * 136 + 64];   // staging 32KB / epilogue 34.8KB
    bf16* As = smem;
    bf16* Bs = smem + 128 * 64;
    const int tid = threadIdx.x;
    const int lane = tid & 63, wv = tid >> 6;
    const int quad = lane >> 4, l16 = lane & 15;
    const int wr = wv >> 1, wc = wv & 1;
    const int rr = lane >> 3, cbl = lane & 7;
    const int arow = tid >> 1, acb = (tid & 1) * 4;
    const int z = blockIdx.y / 6;
    const int n0 = (blockIdx.y % 6) * 128;
    const int m0 = blockIdx.x * 128;
    const float* X    = (z == 0) ? xq : (z == 1) ? xk : xv;
    const float* bias = (z == 0) ? bq : (z == 1) ? bk : bv;
    const bf16*  Wz   = W + (size_t)z * WELEM;
    const float scale = (z == 0) ? 0.125f : 1.0f;

    f32x4 acc[4][4] = {};
    for (int kt = 0; kt < 12; ++kt) {
        if (kt) __syncthreads();
        // A: fp32 load + convert + swizzled LDS write (128 rows x 64 cols)
        {
            const float* ap = X + (size_t)(m0 + arow) * DIMD + kt * 64 + acb * 8;
            for (int i = 0; i < 4; ++i) {
                float4 u = *(const float4*)(ap + i * 8);
                float4 w = *(const float4*)(ap + i * 8 + 4);
                bf16x8 p;
                p[0] = (bf16)u.x; p[1] = (bf16)u.y; p[2] = (bf16)u.z; p[3] = (bf16)u.w;
                p[4] = (bf16)w.x; p[5] = (bf16)w.y; p[6] = (bf16)w.z; p[7] = (bf16)w.w;
                *(bf16x8*)(As + arow * 64 + ((acb + i) ^ (arow & 7)) * 8) = p;
            }
        }
        // B: weights async (128 rows x 64 cols)
        for (int c = 0; c < 4; ++c) {
            const int row = c * 32 + wv * 8 + rr;
            const int cb = cbl ^ (row & 7);
            async16(Wz + (size_t)(n0 + row) * DIMD + kt * 64 + cb * 8,
                    Bs + row * 64 + cbl * 8);
        }
        __syncthreads();
        for (int ks = 0; ks < 2; ++ks) {
            const int kc = ((ks * 4 + quad) ^ (l16 & 7)) * 8;
            bf16x8 af[4], bfr[4];
            for (int t = 0; t < 4; ++t)
                af[t] = *(const bf16x8*)(As + (wr * 64 + t * 16 + l16) * 64 + kc);
            for (int t = 0; t < 4; ++t)
                bfr[t] = *(const bf16x8*)(Bs + (wc * 64 + t * 16 + l16) * 64 + kc);
            for (int ti = 0; ti < 4; ++ti)
                for (int tj = 0; tj < 4; ++tj)
                    acc[ti][tj] = mfma_bf16(af[ti], bfr[tj], acc[ti][tj]);
        }
    }
    __syncthreads();
    const int bb = m0 >> 11, sbase = m0 & 2047;
    bf16* Ot = smem;
    if (z < 2) {
        // Ot[s 128][feat 128] stride 136
        for (int ti = 0; ti < 4; ++ti)
            for (int tj = 0; tj < 4; ++tj) {
                const int featl = wc * 64 + tj * 16 + l16;
                const float bvl = bias[n0 + featl];
                const int sl = wr * 64 + ti * 16 + quad * 4;
                for (int r = 0; r < 4; ++r)
                    Ot[(sl + r) * 136 + featl] = (bf16)((acc[ti][tj][r] + bvl) * scale);
            }
        __syncthreads();
        bf16* Out = (z == 0) ? Qb : Kb;
        for (int it = 0; it < 8; ++it) {
            const int u = it * 256 + tid;        // 128 s x 16 units
            const int s = u >> 4, c8 = u & 15;
            const int feat = n0 + c8 * 8;
            const int h = feat >> 6, dh = feat & 63;
            *(bf16x8*)&Out[((size_t)(bb * NHD + h) * SEQ + sbase + s) * 64 + dh] =
                *(const bf16x8*)&Ot[s * 136 + c8 * 8];
        }
    } else {
        // Ot[feat 128][s 128] stride 136 (transposed for [b][h][dh][s] output)
        for (int ti = 0; ti < 4; ++ti)
            for (int tj = 0; tj < 4; ++tj) {
                const int featl = wc * 64 + tj * 16 + l16;
                const float bvl = bias[n0 + featl];
                const int sl = wr * 64 + ti * 16 + quad * 4;
                bf16x4 pk;
                for (int r = 0; r < 4; ++r) pk[r] = (bf16)(acc[ti][tj][r] + bvl);
                *(bf16x4*)&Ot[featl * 136 + sl] = pk;
            }
        __syncthreads();
        for (int it = 0; it < 8; ++it) {
            const int u = it * 256 + tid;        // 128 feats x 16 units
            const int f = u >> 4, c8 = u & 15;
            const int feat = n0 + f;
            const int h = feat >> 6, dh = feat & 63;
            *(bf16x8*)&Vb[((size_t)(bb * NHD + h) * 64 + dh) * SEQ + sbase + c8 * 8] =
                *(const bf16x8*)&Ot[f * 136 + c8 * 8];
        }
    }
}

// ---------------- flash attention (R2 body verbatim; R3 XCD decode) ----------------
// grid (768) linear: xcd = lin&7; j = lin>>3; qt = j&15; bh = (j>>4)*8 + xcd.
// All 16 q-tiles of one (b,h) on one XCD -> K/V L2-resident.
// Block 256 = 4 waves. Q-tile 128 (each wave owns 32 queries, 2 strips).
// Phase 1: S^T = K.Q^T with K frags direct from global; online softmax; P -> LDS (dbuf).
// Phase 2: O^T += V^T.P^T with V^T frags direct from global. 1 barrier per KV tile.
__global__ __launch_bounds__(256, 3) void attn_kernel(
    const bf16* __restrict__ Qb, const bf16* __restrict__ Kb, const bf16* __restrict__ Vb,
    const int* __restrict__ mask, bf16* __restrict__ CTX) {
    __shared__ __align__(16) bf16 Ps[2][128][72];
    __shared__ float alphas[2][128];
    __shared__ float sadd[2048];
    __shared__ float invs[128];
    __shared__ int anyz_s;
    const int tid = threadIdx.x;
    const int lane = tid & 63, wv = tid >> 6, quad = lane >> 4, l16 = lane & 15;
    const int lin = blockIdx.x;
    const int xcd = lin & 7, j = lin >> 3;
    const int qt = j & 15, pg = j >> 4;
    const int bh = pg * 8 + xcd;                     // 0..47
    const int b = bh / NHD, h = bh % NHD;
    if (tid == 0) anyz_s = 0;
    __syncthreads();
    {
        int4 m0v = *(const int4*)(mask + b * SEQ + tid * 8);
        int4 m1v = *(const int4*)(mask + b * SEQ + tid * 8 + 4);
        float4 f0, f1;
        f0.x = m0v.x ? 0.f : -1e30f; f0.y = m0v.y ? 0.f : -1e30f;
        f0.z = m0v.z ? 0.f : -1e30f; f0.w = m0v.w ? 0.f : -1e30f;
        f1.x = m1v.x ? 0.f : -1e30f; f1.y = m1v.y ? 0.f : -1e30f;
        f1.z = m1v.z ? 0.f : -1e30f; f1.w = m1v.w ? 0.f : -1e30f;
        *(float4*)&sadd[tid * 8] = f0;
        *(float4*)&sadd[tid * 8 + 4] = f1;
        if (!(m0v.x && m0v.y && m0v.z && m0v.w && m1v.x && m1v.y && m1v.z && m1v.w))
            anyz_s = 1;
    }
    // loop-invariant Q fragments (B operand), 2 strips of 16 queries
    bf16x8 qf0[2], qf1[2];
    for (int st = 0; st < 2; ++st) {
        const bf16* qp = Qb + ((size_t)bh * SEQ + qt * 128 + wv * 32 + st * 16 + l16) * 64;
        qf0[st] = *(const bf16x8*)(qp + quad * 8);
        qf1[st] = *(const bf16x8*)(qp + 32 + quad * 8);
    }
    const bf16* Kp = Kb + (size_t)bh * SEQ * 64 + (size_t)l16 * 64 + quad * 8;
    const bf16* Vp = Vb + (size_t)bh * 64 * SEQ + (size_t)(wv * 16 + l16) * SEQ + quad * 8;
    f32x4 acc_o[8] = {};
    float rm[2] = {-1e30f, -1e30f}, rs[2] = {0.f, 0.f};
    __syncthreads();
    const int az = anyz_s;
    for (int kt = 0; kt < SEQ / 64; ++kt) {
        const int buf = kt & 1, k0 = kt * 64;
        // K fragments direct from global (A operand: m=key, k=dh)
        bf16x8 kf0[4], kf1[4];
        for (int jj = 0; jj < 4; ++jj) {
            const bf16* kp = Kp + (size_t)(k0 + jj * 16) * 64;
            kf0[jj] = *(const bf16x8*)kp;
            kf1[jj] = *(const bf16x8*)(kp + 32);
        }
        f32x4 sc[2][4];
        for (int st = 0; st < 2; ++st)
            for (int jj = 0; jj < 4; ++jj) {
                f32x4 zf = {};
                zf = mfma_bf16(kf0[jj], qf0[st], zf);
                sc[st][jj] = mfma_bf16(kf1[jj], qf1[st], zf);
            }
        if (az)
            for (int jj = 0; jj < 4; ++jj) {
                const float4 sa = *(const float4*)&sadd[k0 + jj * 16 + quad * 4];
                for (int st = 0; st < 2; ++st) {
                    sc[st][jj][0] += sa.x; sc[st][jj][1] += sa.y;
                    sc[st][jj][2] += sa.z; sc[st][jj][3] += sa.w;
                }
            }
        for (int st = 0; st < 2; ++st) {
            float tmax = -1e30f;
            for (int jj = 0; jj < 4; ++jj)
                for (int r = 0; r < 4; ++r) tmax = fmaxf(tmax, sc[st][jj][r]);
            tmax = fmaxf(tmax, __shfl_xor(tmax, 16));
            tmax = fmaxf(tmax, __shfl_xor(tmax, 32));
            const float nmax = fmaxf(rm[st], tmax);
            const float alpha = __expf(rm[st] - nmax);
            rm[st] = nmax;
            float tsum = 0.f;
            for (int jj = 0; jj < 4; ++jj) {
                bf16x4 pk;
                for (int r = 0; r < 4; ++r) {
                    const float p = __expf(sc[st][jj][r] - nmax);
                    tsum += p;
                    pk[r] = (bf16)p;
                }
                *(bf16x4*)&Ps[buf][wv * 32 + st * 16 + l16][jj * 16 + quad * 4] = pk;
            }
            tsum += __shfl_xor(tsum, 16);
            tsum += __shfl_xor(tsum, 32);
            rs[st] = rs[st] * alpha + tsum;
            if (lane < 16) alphas[buf][wv * 32 + st * 16 + lane] = alpha;
        }
        // V^T fragments direct from global (A operand: m=dh, k=key)
        bf16x8 vf0 = *(const bf16x8*)(Vp + k0);
        bf16x8 vf1 = *(const bf16x8*)(Vp + k0 + 32);
        __syncthreads();                         // Ps/alphas[buf] visible
        for (int qj = 0; qj < 8; ++qj) {
            const float al = alphas[buf][qj * 16 + l16];
            f32x4 c = acc_o[qj];
            c[0] *= al; c[1] *= al; c[2] *= al; c[3] *= al;
            bf16x8 pf0 = *(const bf16x8*)&Ps[buf][qj * 16 + l16][quad * 8];
            bf16x8 pf1 = *(const bf16x8*)&Ps[buf][qj * 16 + l16][32 + quad * 8];
            c = mfma_bf16(vf0, pf0, c);
            c = mfma_bf16(vf1, pf1, c);
            acc_o[qj] = c;
        }
    }
    if (lane < 16) {
        invs[wv * 32 + lane] = 1.0f / rs[0];
        invs[wv * 32 + 16 + lane] = 1.0f / rs[1];
    }
    __syncthreads();
    for (int qj = 0; qj < 8; ++qj) {
        const float inv = invs[qj * 16 + l16];
        bf16x4 pk;
        for (int r = 0; r < 4; ++r) pk[r] = (bf16)(acc_o[qj][r] * inv);
        const int s = qt * 128 + qj * 16 + l16;
        *(bf16x4*)&CTX[(size_t)(b * SEQ + s) * DIMD + h * 64 + wv * 16 + quad * 4] = pk;
    }
}

// ---------------- output projection: CTX(bf16) @ Wo^T + b -> fp32 ----------------
// Tile 128x64, grid (64, 12) = 768 blocks. (R3-proven)
__global__ __launch_bounds__(256, 4) void oproj_kernel(
    const bf16* __restrict__ ctx, const bf16* __restrict__ wo,
    const float* __restrict__ bo, float* __restrict__ out) {
    __shared__ __align__(16) bf16 smem[128 * 64 + 64 * 64];
    bf16* As = smem;
    bf16* Bs = smem + 128 * 64;
    const int tid = threadIdx.x;
    const int lane = tid & 63, wv = tid >> 6;
    const int quad = lane >> 4, l16 = lane & 15;
    const int wr = wv >> 1, wc = wv & 1;
    const int rr = lane >> 3, cbl = lane & 7;
    const int m0 = blockIdx.x * 128, f0 = blockIdx.y * 64;
    f32x4 acc[4][2] = {};
    for (int kt = 0; kt < 12; ++kt) {
        if (kt) __syncthreads();
        for (int c = 0; c < 4; ++c) {
            const int row = c * 32 + wv * 8 + rr;
            const int cb = cbl ^ (row & 7);
            async16(ctx + (size_t)(m0 + row) * DIMD + kt * 64 + cb * 8,
                    As + row * 64 + cbl * 8);
        }
        for (int c = 0; c < 2; ++c) {
            const int row = c * 32 + wv * 8 + rr;
            const int cb = cbl ^ (row & 7);
            async16(wo + (size_t)(f0 + row) * DIMD + kt * 64 + cb * 8,
                    Bs + row * 64 + cbl * 8);
        }
        __syncthreads();
        for (int ks = 0; ks < 2; ++ks) {
            const int kc = ((ks * 4 + quad) ^ (l16 & 7)) * 8;
            bf16x8 af[4], bfr[2];
            for (int t = 0; t < 4; ++t)
                af[t] = *(const bf16x8*)(As + (wr * 64 + t * 16 + l16) * 64 + kc);
            for (int t = 0; t < 2; ++t)
                bfr[t] = *(const bf16x8*)(Bs + (wc * 32 + t * 16 + l16) * 64 + kc);
            for (int ti = 0; ti < 4; ++ti)
                for (int tj = 0; tj < 2; ++tj)
                    acc[ti][tj] = mfma_bf16(af[ti], bfr[tj], acc[ti][tj]);
        }
    }
    for (int ti = 0; ti < 4; ++ti) {
        const int rowb = m0 + wr * 64 + ti * 16 + quad * 4;
        for (int tj = 0; tj < 2; ++tj) {
            const int feat = f0 + wc * 32 + tj * 16 + l16;
            const float bvl = bo[feat];
            for (int r = 0; r < 4; ++r)
                out[(size_t)(rowb + r) * DIMD + feat] = acc[ti][tj][r] + bvl;
        }
    }
}

extern "C" void kernel_launch(void* const* d_in, const int* in_sizes, int n_in,
                              void* d_out, int out_size, void* d_ws, size_t ws_size,
                              hipStream_t stream) {
    const float* query = (const float*)d_in[0];
    const float* key_t = (const float*)d_in[1];
    const float* value = (const float*)d_in[2];
    const int*   mask  = (const int*)d_in[3];
    const float* q_w = (const float*)d_in[4];
    const float* q_b = (const float*)d_in[5];
    const float* k_w = (const float*)d_in[6];
    const float* k_b = (const float*)d_in[7];
    const float* v_w = (const float*)d_in[8];
    const float* v_b = (const float*)d_in[9];
    const float* o_w = (const float*)d_in[10];
    const float* o_b = (const float*)d_in[11];
    float* out = (float*)d_out;

    bf16* ws  = (bf16*)d_ws;
    bf16* W   = ws;                                  // 4 x WELEM
    bf16* Qb  = ws + (size_t)4 * WELEM;              // [b][h][s][dh]
    bf16* Kb  = Qb + (size_t)MTOT * DIMD;            // [b][h][s][dh]
    bf16* Vb  = Kb + (size_t)MTOT * DIMD;            // [b][h][dh][s]
    bf16* CTX = Vb + (size_t)MTOT * DIMD;            // [b*s][dim]

    convert_w_kernel<<<dim3(WELEM / 1024, 4), 256, 0, stream>>>(q_w, k_w, v_w, o_w, W);
    qkv_kernel<<<dim3(64, 18), 256, 0, stream>>>(
        query, key_t, value, W, q_b, k_b, v_b, Qb, Kb, Vb);
    attn_kernel<<<768, 256, 0, stream>>>(Qb, Kb, Vb, mask, CTX);
    oproj_kernel<<<dim3(64, 12), 256, 0, stream>>>(
        CTX, W + (size_t)3 * WELEM, o_b, out);
}